// Round 3
// baseline (183.067 us; speedup 1.0000x reference)
//
#include <hip/hip_runtime.h>

// Problem dims (fixed by setup_inputs): T=1024, B=8, d=64, n=64
#define T_DIM 1024
#define B_DIM 8
#define D_DIM 64
#define N_DIM 64

typedef float v4f __attribute__((ext_vector_type(4)));

// Workspace layout (floats):
//   w    : [T][B][N]     at 0        (524288 floats, 2 MB)
//   psum : [C][B][D][N]  at 524288   (C*32768 floats; C=32 -> 4 MB)
#define WS_W 0
#define WS_PSUM 524288

// ---------------------------------------------------------------------------
// D: fused decay scan. One block per b (8 blocks x 1024 threads, 16 waves).
// Phase 1: per-chunk log-sums (coalesced 256B rows) -> LDS.
// Phase 2: per-thread prefix from LDS, then emit w[t,b,n] = k * decay.
// ---------------------------------------------------------------------------
template <int C>
__global__ __launch_bounds__(1024) void decay_w_kernel(
    const float* __restrict__ alpha, const float* __restrict__ kk,
    float* __restrict__ ws) {
  constexpr int LEN = T_DIM / C;
  constexpr int CPT = C / 16;  // chunks per thread
  const int b = blockIdx.x;
  const int tid = threadIdx.x;
  const int n = tid & 63;
  const int ci = tid >> 6;  // 0..15

  __shared__ float ls[C][N_DIM];

#pragma unroll
  for (int cc = 0; cc < CPT; ++cc) {
    const int c = cc * 16 + ci;
    float s = 0.f;
#pragma unroll 8
    for (int i = 0; i < LEN; ++i) {
      const int t = c * LEN + i;
      s += logf(fmaxf(alpha[((size_t)t * B_DIM + b) * N_DIM + n], 1e-8f));
    }
    ls[c][n] = s;
  }
  __syncthreads();

#pragma unroll
  for (int cc = 0; cc < CPT; ++cc) {
    const int c = cc * 16 + ci;
    float pre = 0.f, tot = 0.f;
#pragma unroll
    for (int j = 0; j < C; ++j) {
      const float sv = ls[j][n];
      tot += sv;
      if (j < c) pre += sv;
    }
    // Matches reference f32 numerics: expf(tot) underflows -> denom = 1e-8
    const float invden = 1.0f / (expf(tot) + 1e-8f);
    float cum = pre;
#pragma unroll 4
    for (int i = 0; i < LEN; ++i) {
      const size_t idx = ((size_t)(c * LEN + i) * B_DIM + b) * N_DIM + n;
      cum += logf(fmaxf(alpha[idx], 1e-8f));
      ws[WS_W + idx] = kk[idx] * expf(cum) * invden;
    }
  }
}

// ---------------------------------------------------------------------------
// S1: per-chunk partial sums of v[t,b,d]*w[t,b,n].
// Grid = C*8*4 blocks x 256 threads. Thread: d = dt*16 + tid>>4, n0=(tid&15)*4.
// ---------------------------------------------------------------------------
template <int C>
__global__ __launch_bounds__(256) void chunk_psum_kernel(
    const float* __restrict__ v, float* __restrict__ ws) {
  constexpr int LEN = T_DIM / C;
  const int bid = blockIdx.x;
  const int dt = bid & 3;
  const int b  = (bid >> 2) & 7;
  const int c  = bid >> 5;
  const int tid = threadIdx.x;
  const int d  = dt * 16 + (tid >> 4);
  const int n0 = (tid & 15) * 4;

  const float* __restrict__ vp = v + (size_t)b * D_DIM + d;
  const float* __restrict__ wp = ws + WS_W + (size_t)b * N_DIM + n0;

  v4f acc = {0.f, 0.f, 0.f, 0.f};
#pragma unroll 8
  for (int i = 0; i < LEN; ++i) {
    const int t = c * LEN + i;
    const float vv = vp[(size_t)t * (B_DIM * D_DIM)];
    const v4f w4 = *(const v4f*)(wp + (size_t)t * (B_DIM * N_DIM));
    acc.x = fmaf(vv, w4.x, acc.x);
    acc.y = fmaf(vv, w4.y, acc.y);
    acc.z = fmaf(vv, w4.z, acc.z);
    acc.w = fmaf(vv, w4.w, acc.w);
  }
  *(v4f*)(ws + WS_PSUM + (((size_t)c * B_DIM + b) * D_DIM + d) * N_DIM + n0) = acc;
}

// ---------------------------------------------------------------------------
// S2: acc = sum of prior chunk psums, then LEN-step fma+store loop.
// Non-temporal stores: out is write-once, keep L2 for w/v/psum.
// ---------------------------------------------------------------------------
template <int C>
__global__ __launch_bounds__(256) void scan_store_kernel(
    const float* __restrict__ v, const float* __restrict__ ws,
    float* __restrict__ out) {
  constexpr int LEN = T_DIM / C;
  const int bid = blockIdx.x;
  const int dt = bid & 3;
  const int b  = (bid >> 2) & 7;
  const int c  = bid >> 5;
  const int tid = threadIdx.x;
  const int d  = dt * 16 + (tid >> 4);
  const int n0 = (tid & 15) * 4;

  const float* __restrict__ vp = v + (size_t)b * D_DIM + d;
  const float* __restrict__ wp = ws + WS_W + (size_t)b * N_DIM + n0;
  const float* __restrict__ pp = ws + WS_PSUM + ((size_t)b * D_DIM + d) * N_DIM + n0;

  v4f acc = {0.f, 0.f, 0.f, 0.f};
#pragma unroll 4
  for (int j = 0; j < c; ++j) {
    const v4f p = *(const v4f*)(pp + (size_t)j * (B_DIM * D_DIM * N_DIM));
    acc.x += p.x; acc.y += p.y; acc.z += p.z; acc.w += p.w;
  }

#pragma unroll 8
  for (int i = 0; i < LEN; ++i) {
    const int t = c * LEN + i;
    const float vv = vp[(size_t)t * (B_DIM * D_DIM)];
    const v4f w4 = *(const v4f*)(wp + (size_t)t * (B_DIM * N_DIM));
    acc.x = fmaf(vv, w4.x, acc.x);
    acc.y = fmaf(vv, w4.y, acc.y);
    acc.z = fmaf(vv, w4.z, acc.z);
    acc.w = fmaf(vv, w4.w, acc.w);
    __builtin_nontemporal_store(
        acc, (v4f*)(out + (((size_t)t * B_DIM + b) * D_DIM + d) * N_DIM + n0));
  }
}

// ---------------------------------------------------------------------------
extern "C" void kernel_launch(void* const* d_in, const int* in_sizes, int n_in,
                              void* d_out, int out_size, void* d_ws, size_t ws_size,
                              hipStream_t stream) {
  const float* v     = (const float*)d_in[0];
  const float* k     = (const float*)d_in[1];
  const float* alpha = (const float*)d_in[2];
  float* out = (float*)d_out;
  float* ws  = (float*)d_ws;

  // C=32 path needs (524288 + 32*32768)*4 = 6.29 MB of scratch.
  const size_t needed32 = (size_t)(WS_PSUM + 32 * B_DIM * D_DIM * N_DIM) * sizeof(float);
  if (ws_size >= needed32) {
    decay_w_kernel<32><<<B_DIM, 1024, 0, stream>>>(alpha, k, ws);
    chunk_psum_kernel<32><<<32 * 32, 256, 0, stream>>>(v, ws);
    scan_store_kernel<32><<<32 * 32, 256, 0, stream>>>(v, ws, out);
  } else {
    decay_w_kernel<16><<<B_DIM, 1024, 0, stream>>>(alpha, k, ws);
    chunk_psum_kernel<16><<<16 * 32, 256, 0, stream>>>(v, ws);
    scan_store_kernel<16><<<16 * 32, 256, 0, stream>>>(v, ws, out);
  }
}

// Round 4
// 164.780 us; speedup vs baseline: 1.1110x; 1.1110x over previous
//
#include <hip/hip_runtime.h>

// Problem dims (fixed by setup_inputs): T=1024, B=8, d=64, n=64
#define T_DIM 1024
#define B_DIM 8
#define D_DIM 64
#define N_DIM 64

typedef float v4f __attribute__((ext_vector_type(4)));

// Decay scan chunking: 64 chunks of 16 timesteps
#define DC_CHUNKS 64
#define DC_LEN 16

#define SLAB (B_DIM * D_DIM * N_DIM)  // 32768 floats = 128 KB per chunk slab

// Workspace layout (floats), C = outer-cumsum chunk count:
//   w    : [T][B][N]      at 0
//   psum : [C][B][D][N]   at WS_PSUM
//   pxs  : [C][B][D][N]   at WS_PSUM + C*SLAB   (exclusive prefix)
//   lsum : [B][64][N]     at WS_PSUM + 2*C*SLAB
#define WS_W 0
#define WS_PSUM (T_DIM * B_DIM * N_DIM)  // 524288

// ---------------------------------------------------------------------------
// D1: per-(b, t-chunk) sums of log(max(alpha,1e-8)). lane = n, coalesced rows.
// ---------------------------------------------------------------------------
__global__ __launch_bounds__(64) void decay_chunksum_kernel(
    const float* __restrict__ alpha, float* __restrict__ lsum) {
  const int b = blockIdx.x >> 6;
  const int c = blockIdx.x & 63;
  const int n = threadIdx.x;

  float s = 0.f;
#pragma unroll
  for (int i = 0; i < DC_LEN; ++i) {
    const int t = c * DC_LEN + i;
    s += logf(fmaxf(alpha[((size_t)t * B_DIM + b) * N_DIM + n], 1e-8f));
  }
  lsum[((size_t)b * DC_CHUNKS + c) * N_DIM + n] = s;
}

// ---------------------------------------------------------------------------
// D2: per-(b, t-chunk): gather chunk prefix + total from lsum, emit
//     w[t,b,n] = k * expf(prefix) / (expf(total)+1e-8)
// ---------------------------------------------------------------------------
__global__ __launch_bounds__(64) void decay_w_kernel(
    const float* __restrict__ alpha, const float* __restrict__ kk,
    const float* __restrict__ lsum, float* __restrict__ w) {
  const int b = blockIdx.x >> 6;
  const int c = blockIdx.x & 63;
  const int n = threadIdx.x;

  const float* __restrict__ lp = lsum + (size_t)b * DC_CHUNKS * N_DIM + n;
  float pre = 0.f, tot = 0.f;
#pragma unroll 8
  for (int j = 0; j < DC_CHUNKS; ++j) {
    const float sj = lp[(size_t)j * N_DIM];
    pre += (j < c) ? sj : 0.f;
    tot += sj;
  }
  // Matches reference f32 numerics: expf(tot) underflows -> denom = 1e-8
  const float invden = 1.0f / (expf(tot) + 1e-8f);

  float cum = pre;
#pragma unroll
  for (int i = 0; i < DC_LEN; ++i) {
    const int t = c * DC_LEN + i;
    const size_t idx = ((size_t)t * B_DIM + b) * N_DIM + n;
    cum += logf(fmaxf(alpha[idx], 1e-8f));
    w[idx] = kk[idx] * expf(cum) * invden;
  }
}

// ---------------------------------------------------------------------------
// S1: per-chunk partial sums of v[t,b,d]*w[t,b,n].
// Grid = C*B*4 blocks x 256. Thread: d = dt*16 + tid>>4, n0 = (tid&15)*4.
// ---------------------------------------------------------------------------
template <int C>
__global__ __launch_bounds__(256) void chunk_psum_kernel(
    const float* __restrict__ v, float* __restrict__ ws) {
  constexpr int LEN = T_DIM / C;
  const int bid = blockIdx.x;
  const int dt = bid & 3;
  const int b  = (bid >> 2) & 7;
  const int c  = bid >> 5;
  const int tid = threadIdx.x;
  const int d  = dt * 16 + (tid >> 4);
  const int n0 = (tid & 15) * 4;

  const float* __restrict__ vp = v + (size_t)b * D_DIM + d;
  const float* __restrict__ wp = ws + WS_W + (size_t)b * N_DIM + n0;

  v4f acc = {0.f, 0.f, 0.f, 0.f};
#pragma unroll
  for (int i = 0; i < LEN; ++i) {
    const int t = c * LEN + i;
    const float vv = vp[(size_t)t * (B_DIM * D_DIM)];
    const v4f w4 = *(const v4f*)(wp + (size_t)t * (B_DIM * N_DIM));
    acc.x = fmaf(vv, w4.x, acc.x);
    acc.y = fmaf(vv, w4.y, acc.y);
    acc.z = fmaf(vv, w4.z, acc.z);
    acc.w = fmaf(vv, w4.w, acc.w);
  }
  *(v4f*)(ws + WS_PSUM + (((size_t)c * B_DIM + b) * D_DIM + d) * N_DIM + n0) = acc;
}

// ---------------------------------------------------------------------------
// S1b: exclusive prefix over chunk slabs: pxs[c] = sum_{j<c} psum[j].
// 32768 float4-columns? No: SLAB/4 = 8192 float4 columns, 32 blocks x 256.
// ---------------------------------------------------------------------------
template <int C>
__global__ __launch_bounds__(256) void psum_prefix_kernel(float* __restrict__ ws) {
  const int q = blockIdx.x * 256 + threadIdx.x;  // 0..8191 float4 columns
  v4f* __restrict__ ps  = (v4f*)(ws + WS_PSUM);
  v4f* __restrict__ pxs = ps + (size_t)C * (SLAB / 4);

  v4f run = {0.f, 0.f, 0.f, 0.f};
#pragma unroll 8
  for (int c = 0; c < C; ++c) {
    const v4f p = ps[(size_t)c * (SLAB / 4) + q];
    pxs[(size_t)c * (SLAB / 4) + q] = run;
    run.x += p.x; run.y += p.y; run.z += p.z; run.w += p.w;
  }
}

// ---------------------------------------------------------------------------
// S2: acc = pxs[c] (one 16B load), then LEN-step fma + plain float4 store.
// Grid = C*B*4 blocks x 256 -> C=64: 2048 blocks, 8 blocks/CU, 32 waves/CU.
// ---------------------------------------------------------------------------
template <int C>
__global__ __launch_bounds__(256) void scan_store_kernel(
    const float* __restrict__ v, const float* __restrict__ ws,
    float* __restrict__ out) {
  constexpr int LEN = T_DIM / C;
  const int bid = blockIdx.x;
  const int dt = bid & 3;
  const int b  = (bid >> 2) & 7;
  const int c  = bid >> 5;
  const int tid = threadIdx.x;
  const int d  = dt * 16 + (tid >> 4);
  const int n0 = (tid & 15) * 4;

  const float* __restrict__ vp = v + (size_t)b * D_DIM + d;
  const float* __restrict__ wp = ws + WS_W + (size_t)b * N_DIM + n0;
  const float* __restrict__ px = ws + WS_PSUM + (size_t)C * SLAB +
                                 (((size_t)c * B_DIM + b) * D_DIM + d) * N_DIM + n0;

  v4f acc = *(const v4f*)px;

#pragma unroll
  for (int i = 0; i < LEN; ++i) {
    const int t = c * LEN + i;
    const float vv = vp[(size_t)t * (B_DIM * D_DIM)];
    const v4f w4 = *(const v4f*)(wp + (size_t)t * (B_DIM * N_DIM));
    acc.x = fmaf(vv, w4.x, acc.x);
    acc.y = fmaf(vv, w4.y, acc.y);
    acc.z = fmaf(vv, w4.z, acc.z);
    acc.w = fmaf(vv, w4.w, acc.w);
    *(v4f*)(out + (((size_t)t * B_DIM + b) * D_DIM + d) * N_DIM + n0) = acc;
  }
}

// ---------------------------------------------------------------------------
template <int C>
static void launch_all(const float* v, const float* k, const float* alpha,
                       float* out, float* ws, hipStream_t stream) {
  float* lsum = ws + WS_PSUM + (size_t)2 * C * SLAB;
  decay_chunksum_kernel<<<B_DIM * DC_CHUNKS, 64, 0, stream>>>(alpha, lsum);
  decay_w_kernel<<<B_DIM * DC_CHUNKS, 64, 0, stream>>>(alpha, k, lsum, ws + WS_W);
  chunk_psum_kernel<C><<<C * B_DIM * 4, 256, 0, stream>>>(v, ws);
  psum_prefix_kernel<C><<<SLAB / 4 / 256, 256, 0, stream>>>(ws);
  scan_store_kernel<C><<<C * B_DIM * 4, 256, 0, stream>>>(v, ws, out);
}

extern "C" void kernel_launch(void* const* d_in, const int* in_sizes, int n_in,
                              void* d_out, int out_size, void* d_ws, size_t ws_size,
                              hipStream_t stream) {
  const float* v     = (const float*)d_in[0];
  const float* k     = (const float*)d_in[1];
  const float* alpha = (const float*)d_in[2];
  float* out = (float*)d_out;
  float* ws  = (float*)d_ws;

  // C=64 needs (WS_PSUM + 2*64*SLAB + B*64*N)*4 B ~= 19 MB of scratch.
  const size_t need64 =
      (size_t)(WS_PSUM + 2 * 64 * SLAB + B_DIM * DC_CHUNKS * N_DIM) * sizeof(float);
  if (ws_size >= need64) {
    launch_all<64>(v, k, alpha, out, ws, stream);
  } else {
    launch_all<16>(v, k, alpha, out, ws, stream);  // fits in ~6.1 MB
  }
}